// Round 8
// baseline (343.453 us; speedup 1.0000x reference)
//
#include <hip/hip_runtime.h>

typedef unsigned short u16;
typedef unsigned int   u32;
typedef __attribute__((ext_vector_type(8))) short short8;   // 8 bf16 (4 VGPRs)
typedef __attribute__((ext_vector_type(4))) float floatx4;  // MFMA acc

#define T_DIM 4096
#define D_DIM 2048
#define H_DIM 256
#define M_DIM 16384   // B*T
#define NFLAT 8192    // D*W

__device__ __forceinline__ u16 f2bf(float f) {
  union { float f; u32 u; } c; c.f = f;
  u32 x = c.u;
  x += 0x7FFFu + ((x >> 16) & 1u);   // RNE
  return (u16)(x >> 16);
}
__device__ __forceinline__ u32 pk2(float a, float b) {
  return (u32)f2bf(a) | ((u32)f2bf(b) << 16);
}

// async global->LDS, 16B per lane. LDS dest = wave-uniform base + lane*16.
__device__ __forceinline__ void glds16(const void* g, void* l) {
  __builtin_amdgcn_global_load_lds(
      (const __attribute__((address_space(1))) void*)g,
      (__attribute__((address_space(3))) void*)l, 16, 0, 0);
}

// ------------- fused transpose+cvt for BOTH weights (one launch) ------------
__global__ void __launch_bounds__(256) tr_cvt_all(const float* __restrict__ w1,
                                                  u16* __restrict__ w1t,
                                                  const float* __restrict__ w2,
                                                  u16* __restrict__ w2t) {
  __shared__ u16 tile[32][33];
  int bid = blockIdx.x;
  const float* src; u16* dst; int R, C, c0, r0;
  if (bid < 512) {                       // w1 [2048][256] -> w1t [256][2048]
    src = w1; dst = w1t; R = D_DIM; C = H_DIM;
    c0 = (bid & 7) * 32; r0 = (bid >> 3) * 32;
  } else {                               // w2 [256][8192] -> w2t [8192][256]
    int b = bid - 512;
    src = w2; dst = w2t; R = H_DIM; C = NFLAT;
    c0 = (b & 255) * 32; r0 = (b >> 8) * 32;
  }
  const int tx = threadIdx.x & 31;
  const int ty = threadIdx.x >> 5;       // 0..7
  #pragma unroll
  for (int i = ty; i < 32; i += 8)
    tile[i][tx] = f2bf(src[(size_t)(r0 + i) * C + (c0 + tx)]);
  __syncthreads();
  #pragma unroll
  for (int i = ty; i < 32; i += 8)
    dst[(size_t)(c0 + i) * R + (r0 + tx)] = tile[tx][i];
}

// ---------------- GEMM1: h = silu(x @ w1), fp32 x inline-cvt ----------------
// R7-FROZEN (verified winner): 32x256 tile, counted-vmcnt 2-phase, raw
// s_barrier, depth-2 fA register prefetch riding across barriers.
__global__ void __launch_bounds__(256) gemm1_silu(const float* __restrict__ X,   // [M][2048]
                                                  const u16* __restrict__ Bt,    // w1t [256][2048]
                                                  u16* __restrict__ H) {         // [M][256]
  __shared__ __align__(16) u16 As[2][32][64];    //  8 KB
  __shared__ __align__(16) u16 Bs[2][256][64];   // 64 KB
  const int tid  = threadIdx.x;
  const int lane = tid & 63, l15 = lane & 15, quad = lane >> 4;
  const int wv   = tid >> 6;                     // wave = N quadrant (64 cols)
  const int m0   = blockIdx.x * 32;
  const int srow = lane >> 3, sc = lane & 7;     // glds chunk coords

  floatx4 acc[2][4];
  const floatx4 zf = {0.f, 0.f, 0.f, 0.f};
  #pragma unroll
  for (int i = 0; i < 2; ++i)
    #pragma unroll
    for (int j = 0; j < 4; ++j) acc[i][j] = zf;

  float4 fA0[2], fA1[2];   // A fp32 prefetch regs; A(k) lives in slot k&1

#define G1_LOADA(KT, FW)                                                      \
  {                                                                           \
    int row = tid >> 3, g = tid & 7;                                          \
    const float* xs = &X[(size_t)(m0 + row) * D_DIM + (KT) * 64 + g * 8];     \
    FW[0] = *(const float4*)xs;                                               \
    FW[1] = *(const float4*)(xs + 4);                                         \
  }

#define G1_WRITEA(BUF, FW)                                                    \
  {                                                                           \
    int row = tid >> 3, g = tid & 7, c = g ^ (row & 7);                       \
    uint4 pk;                                                                 \
    pk.x = pk2(FW[0].x, FW[0].y);                                             \
    pk.y = pk2(FW[0].z, FW[0].w);                                             \
    pk.z = pk2(FW[1].x, FW[1].y);                                             \
    pk.w = pk2(FW[1].z, FW[1].w);                                             \
    *(uint4*)&As[BUF][row][c * 8] = pk;                                       \
  }

#define G1_STAGEB(KT, BUF)                                                    \
  _Pragma("unroll")                                                           \
  for (int ci = 0; ci < 8; ++ci) {               /* 32 chunks, 8 per wave */  \
    int ch  = wv * 8 + ci;                                                    \
    int row = ch * 8 + srow;                     /* 0..255 = full H */        \
    glds16(&Bt[(size_t)row * D_DIM + (KT) * 64 + (sc ^ (row & 7)) * 8],       \
           (char*)Bs + (BUF) * 32768 + ch * 1024);                            \
  }

#define G1_STAGE_NEXT(T, BUFN, FW)                                            \
  if ((T) + 1 < 32) {                                                         \
    G1_WRITEA(BUFN, FW);                                                      \
    __builtin_amdgcn_sched_barrier(0);                                        \
    G1_STAGEB((T) + 1, BUFN);                                                 \
    __builtin_amdgcn_sched_barrier(0);                                        \
    if ((T) + 3 < 32) { G1_LOADA((T) + 3, FW); }                              \
  }

#define G1_COMPUTE(BUFC)                                                      \
  {                                                                           \
    short8 af[2][2], bfr[4][2];                                               \
    _Pragma("unroll")                                                         \
    for (int ks = 0; ks < 2; ++ks) {                                          \
      _Pragma("unroll")                                                       \
      for (int mi = 0; mi < 2; ++mi) {                                        \
        int row = mi * 16 + l15;                                              \
        af[mi][ks] = *(const short8*)&As[BUFC][row][((ks * 4 + quad) ^ (row & 7)) * 8]; \
      }                                                                       \
      _Pragma("unroll")                                                       \
      for (int ni = 0; ni < 4; ++ni) {                                        \
        int row = wv * 64 + ni * 16 + l15;                                    \
        bfr[ni][ks] = *(const short8*)&Bs[BUFC][row][((ks * 4 + quad) ^ (row & 7)) * 8]; \
      }                                                                       \
    }                                                                         \
    _Pragma("unroll")                                                         \
    for (int ks = 0; ks < 2; ++ks)                                            \
      _Pragma("unroll")                                                       \
      for (int mi = 0; mi < 2; ++mi)                                          \
        _Pragma("unroll")                                                     \
        for (int ni = 0; ni < 4; ++ni)                                        \
          acc[mi][ni] = __builtin_amdgcn_mfma_f32_16x16x32_bf16(af[mi][ks], bfr[ni][ks], acc[mi][ni], 0, 0, 0); \
  }

#define G1_SYNC(T)                                                            \
  if ((T) + 1 < 32) {                                                         \
    if ((T) <= 28) { asm volatile("s_waitcnt vmcnt(2)" ::: "memory"); }       \
    else           { asm volatile("s_waitcnt vmcnt(0)" ::: "memory"); }       \
    asm volatile("s_waitcnt lgkmcnt(0)" ::: "memory");                        \
    __builtin_amdgcn_sched_barrier(0);                                        \
    __builtin_amdgcn_s_barrier();                                             \
    __builtin_amdgcn_sched_barrier(0);                                        \
  }

  G1_LOADA(0, fA0);
  G1_LOADA(1, fA1);
  G1_WRITEA(0, fA0);                 // auto-waits fA0 only (2 newer loads)
  __builtin_amdgcn_sched_barrier(0);
  G1_STAGEB(0, 0);
  __builtin_amdgcn_sched_barrier(0);
  G1_LOADA(2, fA0);
  asm volatile("s_waitcnt vmcnt(2)" ::: "memory");   // glds(0)+fA1 done; fA2 in flight
  asm volatile("s_waitcnt lgkmcnt(0)" ::: "memory"); // ds_write A(0) done
  __builtin_amdgcn_sched_barrier(0);
  __builtin_amdgcn_s_barrier();
  __builtin_amdgcn_sched_barrier(0);

  for (int tt = 0; tt < 32; tt += 2) {
    G1_STAGE_NEXT(tt, 1, fA1);
    G1_COMPUTE(0);
    G1_SYNC(tt);
    G1_STAGE_NEXT(tt + 1, 0, fA0);
    G1_COMPUTE(1);
    G1_SYNC(tt + 1);
  }

  #pragma unroll
  for (int mi = 0; mi < 2; ++mi)
    #pragma unroll
    for (int ni = 0; ni < 4; ++ni)
      #pragma unroll
      for (int r = 0; r < 4; ++r) {
        float v = acc[mi][ni][r];
        v = v / (1.f + __expf(-v));
        int row = m0 + mi * 16 + quad * 4 + r;
        int col = wv * 64 + ni * 16 + l15;
        H[(size_t)row * H_DIM + col] = f2bf(v);
      }
#undef G1_LOADA
#undef G1_WRITEA
#undef G1_STAGEB
#undef G1_STAGE_NEXT
#undef G1_COMPUTE
#undef G1_SYNC
}

// ---- GEMM2 fused: flat = h @ w2 + b2 ; out = silu(conv(flat, x)) ----------
// R1 geometry (128 tokens x 128 flat cols, the only one that worked) but
// TRI-BUFFERED counted-vmcnt pipeline (G1's verified template): BK=32,
// 8 K-iters, As[3]+Bs[3] = 48 KB (3 blocks/CU). Iter t issues STAGE(t+2);
// end-of-iter waits vmcnt(4) per wave (drains STAGE(t+1), leaves STAGE(t+2)
// flying -> 2 iters of HBM latency cover; never vmcnt(0) until tail).
// BK=32 bank swizzle: physical chunk h = g ^ ((row>>1)&3); per-16-lane phase
// each b128 start bank gets exactly 2 lanes (2-way = free, same arithmetic
// family as the R1 swizzle that measured 0 conflicts).
// Buffer rotation safety: STAGE(t+2) overwrites buf last read by
// compute(t-1); issued strictly after the barrier ending iter t-1.
__global__ void __launch_bounds__(256) gemm2_conv_silu(const u16* __restrict__ Hin,   // [M][256] bf16
                                                       const u16* __restrict__ Bt,    // w2t [8192][256] bf16
                                                       const float* __restrict__ bias,// [8192] fp32
                                                       const float* __restrict__ X,   // [M][2048] fp32
                                                       float* __restrict__ Out) {     // [M][2048] fp32
  __shared__ __align__(16) u16 As[3][128][32];   // 24 KB
  __shared__ __align__(16) u16 Bs[3][128][32];   // 24 KB
  const int tid  = threadIdx.x;
  const int lane = tid & 63, l15 = lane & 15, quad = lane >> 4;
  const int wv   = tid >> 6, wy = wv >> 1, wx = wv & 1;
  const int m0   = blockIdx.y * 128;
  const int d0   = blockIdx.x * 32;
  const int rloc = lane >> 2, hh = lane & 3;     // glds slot coords in chunk

  floatx4 acc[4][4];
  const floatx4 zf = {0.f, 0.f, 0.f, 0.f};
  #pragma unroll
  for (int i = 0; i < 4; ++i)
    #pragma unroll
    for (int j = 0; j < 4; ++j) acc[i][j] = zf;

// 8 chunks of 1 KB (16 rows) per matrix per K-tile; 2 per wave per matrix
// => 4 glds per wave per STAGE (vmcnt counts per-wave instructions).
#define G2_STAGE(KT, BUF)                                                     \
  _Pragma("unroll")                                                           \
  for (int ci = 0; ci < 2; ++ci) {                                            \
    int ch  = wv * 2 + ci;                                                    \
    int row = ch * 16 + rloc;                    /* 0..127 */                 \
    int g   = hh ^ ((row >> 1) & 3);             /* pre-swizzled source */    \
    glds16(&Hin[(size_t)(m0 + row) * H_DIM + (KT) * 32 + g * 8],              \
           (char*)As + (BUF) * 8192 + ch * 1024);                             \
    int fc  = (d0 + ((row >> 6) << 4) + (row & 15)) * 4 + ((row >> 4) & 3);   \
    glds16(&Bt[(size_t)fc * H_DIM + (KT) * 32 + g * 8],                       \
           (char*)Bs + (BUF) * 8192 + ch * 1024);                             \
  }

#define G2_COMPUTE(BUF)                                                       \
  {                                                                           \
    short8 af[4], bfr[4];                                                     \
    _Pragma("unroll")                                                         \
    for (int mi = 0; mi < 4; ++mi) {                                          \
      int row = wy * 64 + mi * 16 + l15;                                      \
      int h   = quad ^ ((row >> 1) & 3);                                      \
      af[mi] = *(const short8*)((const char*)As + (BUF) * 8192 + row * 64 + h * 16); \
    }                                                                         \
    _Pragma("unroll")                                                         \
    for (int ni = 0; ni < 4; ++ni) {                                          \
      int row = wx * 64 + ni * 16 + l15;                                      \
      int h   = quad ^ ((row >> 1) & 3);                                      \
      bfr[ni] = *(const short8*)((const char*)Bs + (BUF) * 8192 + row * 64 + h * 16); \
    }                                                                         \
    _Pragma("unroll")                                                         \
    for (int mi = 0; mi < 4; ++mi)                                            \
      _Pragma("unroll")                                                       \
      for (int ni = 0; ni < 4; ++ni)                                          \
        acc[mi][ni] = __builtin_amdgcn_mfma_f32_16x16x32_bf16(af[mi], bfr[ni], acc[mi][ni], 0, 0, 0); \
  }

#define G2_SYNC(NWAIT)                                                        \
  asm volatile("s_waitcnt vmcnt(" #NWAIT ")" ::: "memory");                   \
  asm volatile("s_waitcnt lgkmcnt(0)" ::: "memory");                          \
  __builtin_amdgcn_sched_barrier(0);                                          \
  __builtin_amdgcn_s_barrier();                                               \
  __builtin_amdgcn_sched_barrier(0);

  // prologue: stage K-tiles 0,1; wait own STAGE(0) (4 ops) done, leave STAGE(1)
  G2_STAGE(0, 0);
  __builtin_amdgcn_sched_barrier(0);
  G2_STAGE(1, 1);
  __builtin_amdgcn_sched_barrier(0);
  G2_SYNC(4)

  #pragma unroll
  for (int t = 0; t < 8; ++t) {
    if (t + 2 < 8) {
      G2_STAGE(t + 2, (t + 2) % 3);
      __builtin_amdgcn_sched_barrier(0);
    }
    G2_COMPUTE(t % 3);
    if (t + 1 < 8) {
      if (t + 2 < 8) { G2_SYNC(4) }
      else           { G2_SYNC(0) }
    }
  }
#undef G2_STAGE
#undef G2_COMPUTE
#undef G2_SYNC

  // -------- register epilogue: bias + causal conv + silu, no LDS -----------
  const int d     = d0 + wx * 16 + l15;            // this lane's channel
  const float4 bv = *(const float4*)&bias[(size_t)d * 4];  // taps w=0..3
  const int tbase = m0 & (T_DIM - 1);              // tiles never straddle batch
  const int bbase = m0 - tbase;
  const float* xcol = &X[(size_t)bbase * D_DIM + d];
  float* ocol       = &Out[(size_t)m0 * D_DIM + d];

  #pragma unroll
  for (int mi = 0; mi < 4; ++mi) {
    int t0 = wy * 64 + mi * 16 + quad * 4;         // local token of r=0
    int tq = tbase + t0;                           // token within batch
    float xv[7];                                   // x[tq-3 .. tq+3] for this d
    #pragma unroll
    for (int j = 0; j < 7; ++j) {
      int tt = tq - 3 + j;
      xv[j] = (tt >= 0) ? xcol[(size_t)tt * D_DIM] : 0.f;
    }
    #pragma unroll
    for (int r = 0; r < 4; ++r) {
      float c0 = acc[mi][0][r] + bv.x;
      float c1 = acc[mi][1][r] + bv.y;
      float c2 = acc[mi][2][r] + bv.z;
      float c3 = acc[mi][3][r] + bv.w;
      float o  = c0 * xv[r] + c1 * xv[r + 1] + c2 * xv[r + 2] + c3 * xv[r + 3];
      float y  = o / (1.f + __expf(-o));
      ocol[(size_t)(t0 + r) * D_DIM] = y;
    }
  }
}

extern "C" void kernel_launch(void* const* d_in, const int* in_sizes, int n_in,
                              void* d_out, int out_size, void* d_ws, size_t ws_size,
                              hipStream_t stream) {
  const float* x  = (const float*)d_in[0];   // [4,4096,2048]
  const float* w1 = (const float*)d_in[1];   // [2048,256]
  const float* w2 = (const float*)d_in[2];   // [256,8192]
  const float* b2 = (const float*)d_in[3];   // [8192]
  float* out = (float*)d_out;                // [4,4096,2048]

  // ws layout (u16 elems): w1t 512K | w2t 2M | h 4M  (= ~13.6 MB)
  u16* w1t = (u16*)d_ws;                     // [256][2048]
  u16* w2t = w1t + (size_t)H_DIM * D_DIM;    // [8192][256]
  u16* h   = w2t + (size_t)NFLAT * H_DIM;    // [16384][256]

  tr_cvt_all<<<512 + 2048, 256, 0, stream>>>(w1, w1t, w2, w2t);
  gemm1_silu<<<M_DIM / 32, 256, 0, stream>>>(x, w1t, h);
  gemm2_conv_silu<<<dim3(D_DIM / 32, M_DIM / 128), 256, 0, stream>>>(h, w2t, b2, x, out);
}